// Round 4
// baseline (18889.198 us; speedup 1.0000x reference)
//
#include <hip/hip_runtime.h>

typedef unsigned short u16;
typedef _Float16 f16_t;
typedef f16_t f16x8 __attribute__((ext_vector_type(8)));
typedef float f32x4 __attribute__((ext_vector_type(4)));

#define T_STEPS 256
#define IN_DIM  5
#define ROWS    16      // batch rows per block
#define NBLK    256     // 256 * 16 = B = 4096

// d_ws layout (u16 elements):
//   ws0: [64 nt][9 ks][64 lane][8 e] = 294912   (w_hh0, ks=8 appends w_ih0 zero-padded)
//   ws1: [64 nt][8 ks][64 lane][8 e] = 262144   @ 294912   (w_ih1)
//   ws2: [64 nt][8 ks][64 lane][8 e] = 262144   @ 557056   (w_hh1)
//   biases (float) @ byte 1638400: bias0[1024]=b_ih0+b_hh0, bias1[1024]=b_ih1+b_hh1

__device__ __forceinline__ float sigf(float x)  { return 1.0f / (1.0f + __expf(-x)); }
__device__ __forceinline__ float tanh_f(float x){ return 1.0f - 2.0f / (__expf(2.0f * x) + 1.0f); }

// LDS-visibility barrier, lgkm-only (no vmem drain). Proven in round 3:
// memory clobbers on BOTH sides of s_barrier + sched_barrier(0) so no LDS
// access can be hoisted across the rendezvous at IR or MIR level.
#define BARRIER() do { \
    asm volatile("s_waitcnt lgkmcnt(0)" ::: "memory"); \
    __builtin_amdgcn_s_barrier(); \
    asm volatile("" ::: "memory"); \
    __builtin_amdgcn_sched_barrier(0); \
} while (0)

__global__ void prep_kernel(const float* __restrict__ wih0, const float* __restrict__ whh0,
                            const float* __restrict__ wih1, const float* __restrict__ whh1,
                            const float* __restrict__ bih0, const float* __restrict__ bhh0,
                            const float* __restrict__ bih1, const float* __restrict__ bhh1,
                            u16* __restrict__ wsw, float* __restrict__ biases)
{
    int j = blockIdx.x * blockDim.x + threadIdx.x;
    if (j < 36864) {                              // ws0
        int nt = j / (9 * 64); int rem = j - nt * 9 * 64;
        int ks = rem >> 6; int lane = rem & 63;
        int n = nt * 16 + (lane & 15);
        u16 tmp[8];
#pragma unroll
        for (int e = 0; e < 8; ++e) {
            int kloc = ((lane >> 4) << 3) + e;
            float v;
            if (ks < 8) v = whh0[n * 256 + ks * 32 + kloc];
            else        v = (kloc < IN_DIM) ? wih0[n * IN_DIM + kloc] : 0.0f;
            tmp[e] = __builtin_bit_cast(u16, (f16_t)v);
        }
        *(uint4*)(wsw + (size_t)j * 8) = *(uint4*)tmp;
    } else if (j < 69632) {                       // ws1
        int q = j - 36864;
        int nt = q / (8 * 64); int rem = q - nt * 8 * 64;
        int ks = rem >> 6; int lane = rem & 63;
        int n = nt * 16 + (lane & 15);
        u16 tmp[8];
#pragma unroll
        for (int e = 0; e < 8; ++e) {
            int kloc = ((lane >> 4) << 3) + e;
            float v = wih1[n * 256 + ks * 32 + kloc];
            tmp[e] = __builtin_bit_cast(u16, (f16_t)v);
        }
        *(uint4*)(wsw + 294912 + (size_t)q * 8) = *(uint4*)tmp;
    } else if (j < 102400) {                      // ws2
        int q = j - 69632;
        int nt = q / (8 * 64); int rem = q - nt * 8 * 64;
        int ks = rem >> 6; int lane = rem & 63;
        int n = nt * 16 + (lane & 15);
        u16 tmp[8];
#pragma unroll
        for (int e = 0; e < 8; ++e) {
            int kloc = ((lane >> 4) << 3) + e;
            float v = whh1[n * 256 + ks * 32 + kloc];
            tmp[e] = __builtin_bit_cast(u16, (f16_t)v);
        }
        *(uint4*)(wsw + 557056 + (size_t)q * 8) = *(uint4*)tmp;
    } else if (j < 103424) {                      // bias0
        int i = j - 102400;
        biases[i] = bih0[i] + bhh0[i];
    } else if (j < 104448) {                      // bias1
        int i = j - 103424;
        biases[1024 + i] = bih1[i] + bhh1[i];
    }
}

__global__ __launch_bounds__(1024, 4) void lstm_fused(
    const float* __restrict__ x, const u16* __restrict__ wsw,
    const float* __restrict__ biases, const float* __restrict__ fcw_g,
    const float* __restrict__ fcb_g, float* __restrict__ out)
{
    __shared__ u16 h0b[2 * ROWS * 256];   // fp16 bits, row stride 512B, XOR-swizzled
    __shared__ u16 h1b[2 * ROWS * 256];
    __shared__ u16 xbb[2 * ROWS * 32];    // x_t staged, zero-padded

    const int tid  = threadIdx.x;
    const int wv   = tid >> 6;         // wave 0..15: owns hidden cols [16wv, 16wv+16)
    const int lane = tid & 63;
    const int lrow = lane & 15;
    const int lkg  = lane >> 4;
    const int r0   = blockIdx.x * ROWS;

    const u16* ws0 = wsw;
    const u16* ws1 = wsw + 294912;
    const u16* ws2 = wsw + 557056;
    const float* bias0 = biases;
    const float* bias1 = biases + 1024;

    int o0[4], o12[4];
#pragma unroll
    for (int g = 0; g < 4; ++g) {
        int nt = g * 16 + wv;
        o0[g]  = nt * 9 * 512 + lane * 8;
        o12[g] = nt * 8 * 512 + lane * 8;
    }

    // ---- resident weights: 100 f16x8 fragments = 400 VGPRs/lane ----
    f16x8 w0[9][4], w1[8][4], w2[8][4];
#pragma unroll
    for (int ks = 0; ks < 9; ++ks)
#pragma unroll
        for (int g = 0; g < 4; ++g)
            w0[ks][g] = *(const f16x8*)(ws0 + o0[g] + ks * 512);
#pragma unroll
    for (int ks = 0; ks < 8; ++ks)
#pragma unroll
        for (int g = 0; g < 4; ++g) {
            w1[ks][g] = *(const f16x8*)(ws1 + o12[g] + ks * 512);
            w2[ks][g] = *(const f16x8*)(ws2 + o12[g] + ks * 512);
        }

    float bi0[4], bi1[4];
#pragma unroll
    for (int g = 0; g < 4; ++g) {
        bi0[g] = bias0[g * 256 + wv * 16 + lrow];
        bi1[g] = bias1[g * 256 + wv * 16 + lrow];
    }
    float fcw[4];
#pragma unroll
    for (int r = 0; r < 4; ++r) fcw[r] = fcw_g[lane * 4 + r];
    const float fcb = fcb_g[0];

    // zero LDS state + xb pads
    for (int i = tid; i < 2 * ROWS * 256; i += 1024) { h0b[i] = 0; h1b[i] = 0; }
    xbb[tid] = 0;                       // 1024 threads cover all 1024 xb entries
    __syncthreads();
    // stage x_0 into xb buffer 0
    const int xrow = tid / IN_DIM, xk = tid - (tid / IN_DIM) * IN_DIM;
    if (tid < ROWS * IN_DIM) {
        float v = x[((size_t)(r0 + xrow) * T_STEPS + 0) * IN_DIM + xk];
        int byteo = xrow * 64 + ((2 * xk) ^ ((xrow & 3) << 4));
        *(u16*)((char*)xbb + byteo) = __builtin_bit_cast(u16, (f16_t)v);
    }

    float c0[4] = {0.f, 0.f, 0.f, 0.f};
    float c1[4] = {0.f, 0.f, 0.f, 0.f};

    __syncthreads();

    const int aswz = (lrow & 7) << 4;
    const int xswz = (lrow & 3) << 4;

#pragma unroll 1
    for (int t = 0; t < T_STEPS; ++t) {
        const int p = t & 1;
        const u16* h0p = h0b + p * (ROWS * 256);
        const u16* h1p = h1b + p * (ROWS * 256);
        u16* h0w = h0b + (p ^ 1) * (ROWS * 256);
        u16* h1w = h1b + (p ^ 1) * (ROWS * 256);
        const u16* xbp = xbb + p * (ROWS * 32);
        u16* xbw = xbb + (p ^ 1) * (ROWS * 32);

        // issue x_{t+1} load early; latency hides under GEMM0
        float xv = 0.0f;
        if (t + 1 < T_STEPS && tid < ROWS * IN_DIM)
            xv = x[((size_t)(r0 + xrow) * T_STEPS + (t + 1)) * IN_DIM + xk];

        // ---- GEMM0: gates0 = [h0 | x_t] @ [w_hh0 | w_ih0]^T ----
        f32x4 acc[4] = {};
#pragma unroll
        for (int ks = 0; ks < 8; ++ks) {
            int ao = (ks * 64 + lkg * 16) ^ aswz;
            f16x8 a0 = *(const f16x8*)((const char*)h0p + lrow * 512 + ao);
#pragma unroll
            for (int g = 0; g < 4; ++g)
                acc[g] = __builtin_amdgcn_mfma_f32_16x16x32_f16(a0, w0[ks][g], acc[g], 0, 0, 0);
        }
        {
            int ao = (lkg * 16) ^ xswz;
            f16x8 a0 = *(const f16x8*)((const char*)xbp + lrow * 64 + ao);
#pragma unroll
            for (int g = 0; g < 4; ++g)
                acc[g] = __builtin_amdgcn_mfma_f32_16x16x32_f16(a0, w0[8][g], acc[g], 0, 0, 0);
        }

        // ---- epilogue 0: h0_new, c0; stage x_{t+1} ----
#pragma unroll
        for (int r = 0; r < 4; ++r) {
            float ig = acc[0][r] + bi0[0];
            float fg = acc[1][r] + bi0[1];
            float gg = acc[2][r] + bi0[2];
            float og = acc[3][r] + bi0[3];
            float c  = sigf(fg) * c0[r] + sigf(ig) * tanh_f(gg);
            c0[r] = c;
            float h  = sigf(og) * tanh_f(c);
            int row  = lkg * 4 + r;
            int byteo = row * 512 + (((wv * 16 + lrow) * 2) ^ ((row & 7) << 4));
            *(u16*)((char*)h0w + byteo) = __builtin_bit_cast(u16, (f16_t)h);
        }
        if (t + 1 < T_STEPS && tid < ROWS * IN_DIM) {
            int byteo = xrow * 64 + ((2 * xk) ^ ((xrow & 3) << 4));
            *(u16*)((char*)xbw + byteo) = __builtin_bit_cast(u16, (f16_t)xv);
        }

        BARRIER();   // BAR1: h0_new + x_{t+1} visible

        // ---- GEMM1: gates1 = h0_new @ w_ih1^T + h1 @ w_hh1^T ----
        f32x4 acc1[4] = {};
#pragma unroll
        for (int ks = 0; ks < 8; ++ks) {
            int ao = (ks * 64 + lkg * 16) ^ aswz;
            f16x8 a0 = *(const f16x8*)((const char*)h0w + lrow * 512 + ao);
#pragma unroll
            for (int g = 0; g < 4; ++g)
                acc1[g] = __builtin_amdgcn_mfma_f32_16x16x32_f16(a0, w1[ks][g], acc1[g], 0, 0, 0);
        }
#pragma unroll
        for (int ks = 0; ks < 8; ++ks) {
            int ao = (ks * 64 + lkg * 16) ^ aswz;
            f16x8 a0 = *(const f16x8*)((const char*)h1p + lrow * 512 + ao);
#pragma unroll
            for (int g = 0; g < 4; ++g)
                acc1[g] = __builtin_amdgcn_mfma_f32_16x16x32_f16(a0, w2[ks][g], acc1[g], 0, 0, 0);
        }

        // ---- epilogue 1: h1_new, c1 ----
#pragma unroll
        for (int r = 0; r < 4; ++r) {
            float ig = acc1[0][r] + bi1[0];
            float fg = acc1[1][r] + bi1[1];
            float gg = acc1[2][r] + bi1[2];
            float og = acc1[3][r] + bi1[3];
            float c  = sigf(fg) * c1[r] + sigf(ig) * tanh_f(gg);
            c1[r] = c;
            float h  = sigf(og) * tanh_f(c);
            int row  = lkg * 4 + r;
            int byteo = row * 512 + (((wv * 16 + lrow) * 2) ^ ((row & 7) << 4));
            *(u16*)((char*)h1w + byteo) = __builtin_bit_cast(u16, (f16_t)h);
        }

        BARRIER();   // BAR2: h1_new visible

        // ---- FC output: wave wv handles batch row wv ----
        {
            int byteo = wv * 512 + ((lane * 8) ^ ((wv & 7) << 4));
            uint2 raw = *(const uint2*)((const char*)h1w + byteo);
            float s = (float)__builtin_bit_cast(f16_t, (u16)(raw.x & 0xffff)) * fcw[0]
                    + (float)__builtin_bit_cast(f16_t, (u16)(raw.x >> 16))    * fcw[1]
                    + (float)__builtin_bit_cast(f16_t, (u16)(raw.y & 0xffff)) * fcw[2]
                    + (float)__builtin_bit_cast(f16_t, (u16)(raw.y >> 16))    * fcw[3];
#pragma unroll
            for (int off = 32; off > 0; off >>= 1) s += __shfl_xor(s, off);
            if (lane == 0) out[(size_t)(r0 + wv) * T_STEPS + t] = s + fcb;
        }
    }
}

extern "C" void kernel_launch(void* const* d_in, const int* in_sizes, int n_in,
                              void* d_out, int out_size, void* d_ws, size_t ws_size,
                              hipStream_t stream)
{
    const float* x    = (const float*)d_in[0];
    const float* wih0 = (const float*)d_in[1];
    const float* whh0 = (const float*)d_in[2];
    const float* bih0 = (const float*)d_in[3];
    const float* bhh0 = (const float*)d_in[4];
    const float* wih1 = (const float*)d_in[5];
    const float* whh1 = (const float*)d_in[6];
    const float* bih1 = (const float*)d_in[7];
    const float* bhh1 = (const float*)d_in[8];
    const float* fcw  = (const float*)d_in[9];
    const float* fcb  = (const float*)d_in[10];

    u16* wsw      = (u16*)d_ws;
    float* biases = (float*)((char*)d_ws + 1638400);

    prep_kernel<<<408, 256, 0, stream>>>(wih0, whh0, wih1, whh1,
                                         bih0, bhh0, bih1, bhh1, wsw, biases);
    lstm_fused<<<NBLK, 1024, 0, stream>>>(x, wsw, biases, fcw, fcb, (float*)d_out);
}

// Round 5
// 15058.234 us; speedup vs baseline: 1.2544x; 1.2544x over previous
//
#include <hip/hip_runtime.h>

typedef unsigned short u16;
typedef _Float16 f16_t;
typedef f16_t f16x8 __attribute__((ext_vector_type(8)));
typedef float f32x4 __attribute__((ext_vector_type(4)));

#define T_STEPS 256
#define IN_DIM  5
#define ROWS    32      // batch rows per block
#define NBLK    128     // 128 * 32 = B = 4096

// d_ws layout (u16 elements):
//   ws0: [64 nt][9 ks][64 lane][8 e] = 294912   (w_hh0, ks=8 appends w_ih0 zero-padded)
//   ws1: [64 nt][8 ks][64 lane][8 e] = 262144   @ 294912   (w_ih1)
//   ws2: [64 nt][8 ks][64 lane][8 e] = 262144   @ 557056   (w_hh1)
//   biases (float) @ byte 1638400: bias0[1024]=b_ih0+b_hh0, bias1[1024]=b_ih1+b_hh1
//   barrier counter (uint) @ byte 1646592 (zeroed by prep_kernel every launch)

__device__ __forceinline__ float sigf(float x)  { return 1.0f / (1.0f + __expf(-x)); }
__device__ __forceinline__ float tanh_f(float x){ return 1.0f - 2.0f / (__expf(2.0f * x) + 1.0f); }

// LDS-visibility barrier, lgkm-only (no vmem drain). Proven in round 3:
// memory clobbers on BOTH sides of s_barrier + sched_barrier(0) so no LDS
// access can be hoisted across the rendezvous at IR or MIR level.
#define BARRIER() do { \
    asm volatile("s_waitcnt lgkmcnt(0)" ::: "memory"); \
    __builtin_amdgcn_s_barrier(); \
    asm volatile("" ::: "memory"); \
    __builtin_amdgcn_sched_barrier(0); \
} while (0)

__global__ void prep_kernel(const float* __restrict__ wih0, const float* __restrict__ whh0,
                            const float* __restrict__ wih1, const float* __restrict__ whh1,
                            const float* __restrict__ bih0, const float* __restrict__ bhh0,
                            const float* __restrict__ bih1, const float* __restrict__ bhh1,
                            u16* __restrict__ wsw, float* __restrict__ biases)
{
    int j = blockIdx.x * blockDim.x + threadIdx.x;
    if (j < 36864) {                              // ws0
        int nt = j / (9 * 64); int rem = j - nt * 9 * 64;
        int ks = rem >> 6; int lane = rem & 63;
        int n = nt * 16 + (lane & 15);
        u16 tmp[8];
#pragma unroll
        for (int e = 0; e < 8; ++e) {
            int kloc = ((lane >> 4) << 3) + e;
            float v;
            if (ks < 8) v = whh0[n * 256 + ks * 32 + kloc];
            else        v = (kloc < IN_DIM) ? wih0[n * IN_DIM + kloc] : 0.0f;
            tmp[e] = __builtin_bit_cast(u16, (f16_t)v);
        }
        *(uint4*)(wsw + (size_t)j * 8) = *(uint4*)tmp;
    } else if (j < 69632) {                       // ws1
        int q = j - 36864;
        int nt = q / (8 * 64); int rem = q - nt * 8 * 64;
        int ks = rem >> 6; int lane = rem & 63;
        int n = nt * 16 + (lane & 15);
        u16 tmp[8];
#pragma unroll
        for (int e = 0; e < 8; ++e) {
            int kloc = ((lane >> 4) << 3) + e;
            float v = wih1[n * 256 + ks * 32 + kloc];
            tmp[e] = __builtin_bit_cast(u16, (f16_t)v);
        }
        *(uint4*)(wsw + 294912 + (size_t)q * 8) = *(uint4*)tmp;
    } else if (j < 102400) {                      // ws2
        int q = j - 69632;
        int nt = q / (8 * 64); int rem = q - nt * 8 * 64;
        int ks = rem >> 6; int lane = rem & 63;
        int n = nt * 16 + (lane & 15);
        u16 tmp[8];
#pragma unroll
        for (int e = 0; e < 8; ++e) {
            int kloc = ((lane >> 4) << 3) + e;
            float v = whh1[n * 256 + ks * 32 + kloc];
            tmp[e] = __builtin_bit_cast(u16, (f16_t)v);
        }
        *(uint4*)(wsw + 557056 + (size_t)q * 8) = *(uint4*)tmp;
    } else if (j < 103424) {                      // bias0
        int i = j - 102400;
        biases[i] = bih0[i] + bhh0[i];
    } else if (j < 104448) {                      // bias1
        int i = j - 103424;
        biases[1024 + i] = bih1[i] + bhh1[i];
    } else if (j < 104452) {                      // lockstep barrier counters
        ((unsigned*)(biases + 2048))[j - 104448] = 0u;
    }
}

__global__ __launch_bounds__(1024, 4) void lstm_fused(
    const float* __restrict__ x, const u16* __restrict__ wsw,
    const float* __restrict__ biases, const float* __restrict__ fcw_g,
    const float* __restrict__ fcb_g, float* __restrict__ out,
    unsigned* __restrict__ bar)
{
    extern __shared__ char smem[];
    u16* h0b = (u16*)smem;             // [2][32][256] fp16, row stride 512B, XOR-swizzled
    u16* h1b = (u16*)(smem + 32768);   // [2][32][256]
    u16* xbb = (u16*)(smem + 65536);   // [2][32][32]  x_t staged, zero-padded

    const int tid  = threadIdx.x;
    const int wv   = tid >> 6;         // wave 0..15: owns hidden cols [16wv, 16wv+16)
    const int lane = tid & 63;
    const int lrow = lane & 15;
    const int lkg  = lane >> 4;
    const int r0   = blockIdx.x * ROWS;

    const u16* ws0 = wsw;
    const u16* ws1 = wsw + 294912;
    const u16* ws2 = wsw + 557056;
    const float* bias0 = biases;
    const float* bias1 = biases + 1024;

    int o0[4], o12[4];
#pragma unroll
    for (int g = 0; g < 4; ++g) {
        int nt = g * 16 + wv;
        o0[g]  = nt * 9 * 512 + lane * 8;
        o12[g] = nt * 8 * 512 + lane * 8;
    }
    float bi0[4], bi1[4];
#pragma unroll
    for (int g = 0; g < 4; ++g) {
        bi0[g] = bias0[g * 256 + wv * 16 + lrow];
        bi1[g] = bias1[g * 256 + wv * 16 + lrow];
    }
    float fcw[4];
#pragma unroll
    for (int r = 0; r < 4; ++r) fcw[r] = fcw_g[lane * 4 + r];
    const float fcb = fcb_g[0];

    // zero h0[0], h1[0]; zero both xb buffers
    for (int i = tid; i < 8192; i += 1024) { h0b[i] = 0; h1b[i] = 0; }
    for (int i = tid; i < 2048; i += 1024) xbb[i] = 0;
    __syncthreads();   // zeroing visible before x_0 staging
    // stage x_0 into xb buffer 0
    if (tid < ROWS * IN_DIM) {
        int row = tid / IN_DIM, k = tid - (tid / IN_DIM) * IN_DIM;
        float v = x[((size_t)(r0 + row) * T_STEPS + 0) * IN_DIM + k];
        int byteo = row * 64 + ((2 * k) ^ ((row & 3) << 4));
        *(u16*)((char*)xbb + byteo) = __builtin_bit_cast(u16, (f16_t)v);
    }

    float c0[2][4] = {{0.f,0.f,0.f,0.f},{0.f,0.f,0.f,0.f}};
    float c1[2][4] = {{0.f,0.f,0.f,0.f},{0.f,0.f,0.f,0.f}};

    // start the B-fragment prefetch chain: GEMM0 ks=0
    f16x8 bq[4];
#pragma unroll
    for (int g = 0; g < 4; ++g) bq[g] = *(const f16x8*)(ws0 + o0[g]);

    __syncthreads();

    const int aswz = (lrow & 7) << 4;
    const int xswz = (lrow & 3) << 4;

#pragma unroll 1
    for (int t = 0; t < T_STEPS; ++t) {
        // ---- lockstep pacing barrier: keep all blocks' weight streams in
        // phase so the shared 1.6 MB/step stream stays L2-resident. Pacing
        // only — weights are read-only, h-state is block-local, so there is
        // no memory-ordering requirement. All 128 blocks are co-resident
        // (1 block/CU by LDS), so the spin cannot deadlock.
        if (tid == 0) {
            __hip_atomic_fetch_add(bar, 1u, __ATOMIC_RELAXED, __HIP_MEMORY_SCOPE_AGENT);
            const unsigned tgt = (unsigned)NBLK * (unsigned)(t + 1);
            while (__hip_atomic_load(bar, __ATOMIC_RELAXED, __HIP_MEMORY_SCOPE_AGENT) < tgt)
                __builtin_amdgcn_s_sleep(2);
        }
        __syncthreads();

        const int p = t & 1;
        const u16* h0p = h0b + p * 8192;          // layer-0 h state (old)
        const u16* h1p = h1b + p * 8192;          // layer-1 h state (old)
        u16* h0w = h0b + (p ^ 1) * 8192;          // layer-0 h new
        u16* h1w = h1b + (p ^ 1) * 8192;          // layer-1 h new
        const u16* xbp = xbb + p * 1024;
        u16* xbw = xbb + (p ^ 1) * 1024;

        // ---- GEMM0: gates0 = [h0 | x_t] @ [w_hh0 | w_ih0]^T ----
        f32x4 acc[2][4] = {};
#pragma unroll
        for (int ks = 0; ks < 9; ++ks) {
            f16x8 a0, a1;
            if (ks < 8) {
                int ao = (ks * 64 + lkg * 16) ^ aswz;
                a0 = *(const f16x8*)((const char*)h0p + lrow * 512 + ao);
                a1 = *(const f16x8*)((const char*)h0p + (16 + lrow) * 512 + ao);
            } else {
                int ao = (lkg * 16) ^ xswz;
                a0 = *(const f16x8*)((const char*)xbp + lrow * 64 + ao);
                a1 = *(const f16x8*)((const char*)xbp + (16 + lrow) * 64 + ao);
            }
            f16x8 bc[4];
#pragma unroll
            for (int g = 0; g < 4; ++g) bc[g] = bq[g];
#pragma unroll
            for (int g = 0; g < 4; ++g)
                bq[g] = (ks < 8) ? *(const f16x8*)(ws0 + o0[g] + (ks + 1) * 512)
                                 : *(const f16x8*)(ws1 + o12[g]);   // prefetch GEMM1 ks0
#pragma unroll
            for (int g = 0; g < 4; ++g) {
                acc[0][g] = __builtin_amdgcn_mfma_f32_16x16x32_f16(a0, bc[g], acc[0][g], 0, 0, 0);
                acc[1][g] = __builtin_amdgcn_mfma_f32_16x16x32_f16(a1, bc[g], acc[1][g], 0, 0, 0);
            }
        }

        // ---- epilogue 0: h0_new, c0; also stage x_{t+1} ----
#pragma unroll
        for (int m = 0; m < 2; ++m)
#pragma unroll
        for (int r = 0; r < 4; ++r) {
            float ig = acc[m][0][r] + bi0[0];
            float fg = acc[m][1][r] + bi0[1];
            float gg = acc[m][2][r] + bi0[2];
            float og = acc[m][3][r] + bi0[3];
            float c  = sigf(fg) * c0[m][r] + sigf(ig) * tanh_f(gg);
            c0[m][r] = c;
            float h  = sigf(og) * tanh_f(c);
            int row  = m * 16 + lkg * 4 + r;
            int byteo = row * 512 + (((wv * 16 + lrow) * 2) ^ ((row & 7) << 4));
            *(u16*)((char*)h0w + byteo) = __builtin_bit_cast(u16, (f16_t)h);
        }
        if (t + 1 < T_STEPS && tid < ROWS * IN_DIM) {
            int row = tid / IN_DIM, k = tid - (tid / IN_DIM) * IN_DIM;
            float v = x[((size_t)(r0 + row) * T_STEPS + (t + 1)) * IN_DIM + k];
            int byteo = row * 64 + ((2 * k) ^ ((row & 3) << 4));
            *(u16*)((char*)xbw + byteo) = __builtin_bit_cast(u16, (f16_t)v);
        }

        BARRIER();   // BAR1: h0_new + x_{t+1} visible; weight loads stay in flight

        // ---- GEMM1: gates1 = h0_new @ w_ih1^T + h1 @ w_hh1^T ----
        f32x4 acc1[2][4] = {};
#pragma unroll
        for (int ks = 0; ks < 16; ++ks) {
            const int kk = ks & 7;
            const u16* hsrc = (ks < 8) ? h0w : h1p;
            int ao = (kk * 64 + lkg * 16) ^ aswz;
            f16x8 a0 = *(const f16x8*)((const char*)hsrc + lrow * 512 + ao);
            f16x8 a1 = *(const f16x8*)((const char*)hsrc + (16 + lrow) * 512 + ao);
            f16x8 bc[4];
#pragma unroll
            for (int g = 0; g < 4; ++g) bc[g] = bq[g];
#pragma unroll
            for (int g = 0; g < 4; ++g)
                bq[g] = (ks < 7)  ? *(const f16x8*)(ws1 + o12[g] + (ks + 1) * 512)
                      : (ks == 7) ? *(const f16x8*)(ws2 + o12[g])
                      : (ks < 15) ? *(const f16x8*)(ws2 + o12[g] + (kk + 1) * 512)
                                  : *(const f16x8*)(ws0 + o0[g]);  // prefetch next-t GEMM0
#pragma unroll
            for (int g = 0; g < 4; ++g) {
                acc1[0][g] = __builtin_amdgcn_mfma_f32_16x16x32_f16(a0, bc[g], acc1[0][g], 0, 0, 0);
                acc1[1][g] = __builtin_amdgcn_mfma_f32_16x16x32_f16(a1, bc[g], acc1[1][g], 0, 0, 0);
            }
        }

        // ---- epilogue 1: h1_new, c1 ----
#pragma unroll
        for (int m = 0; m < 2; ++m)
#pragma unroll
        for (int r = 0; r < 4; ++r) {
            float ig = acc1[m][0][r] + bi1[0];
            float fg = acc1[m][1][r] + bi1[1];
            float gg = acc1[m][2][r] + bi1[2];
            float og = acc1[m][3][r] + bi1[3];
            float c  = sigf(fg) * c1[m][r] + sigf(ig) * tanh_f(gg);
            c1[m][r] = c;
            float h  = sigf(og) * tanh_f(c);
            int row  = m * 16 + lkg * 4 + r;
            int byteo = row * 512 + (((wv * 16 + lrow) * 2) ^ ((row & 7) << 4));
            *(u16*)((char*)h1w + byteo) = __builtin_bit_cast(u16, (f16_t)h);
        }

        BARRIER();   // BAR2: h1_new visible

        // ---- FC output: wave wv handles batch rows {wv, wv+16} ----
#pragma unroll
        for (int m = 0; m < 2; ++m) {
            int row = wv + m * 16;
            int byteo = row * 512 + ((lane * 8) ^ ((row & 7) << 4));
            uint2 raw = *(const uint2*)((const char*)h1w + byteo);
            float s = (float)__builtin_bit_cast(f16_t, (u16)(raw.x & 0xffff)) * fcw[0]
                    + (float)__builtin_bit_cast(f16_t, (u16)(raw.x >> 16))    * fcw[1]
                    + (float)__builtin_bit_cast(f16_t, (u16)(raw.y & 0xffff)) * fcw[2]
                    + (float)__builtin_bit_cast(f16_t, (u16)(raw.y >> 16))    * fcw[3];
#pragma unroll
            for (int off = 32; off > 0; off >>= 1) s += __shfl_xor(s, off);
            if (lane == 0) out[(size_t)(r0 + row) * T_STEPS + t] = s + fcb;
        }
    }
}

extern "C" void kernel_launch(void* const* d_in, const int* in_sizes, int n_in,
                              void* d_out, int out_size, void* d_ws, size_t ws_size,
                              hipStream_t stream)
{
    const float* x    = (const float*)d_in[0];
    const float* wih0 = (const float*)d_in[1];
    const float* whh0 = (const float*)d_in[2];
    const float* bih0 = (const float*)d_in[3];
    const float* bhh0 = (const float*)d_in[4];
    const float* wih1 = (const float*)d_in[5];
    const float* whh1 = (const float*)d_in[6];
    const float* bih1 = (const float*)d_in[7];
    const float* bhh1 = (const float*)d_in[8];
    const float* fcw  = (const float*)d_in[9];
    const float* fcb  = (const float*)d_in[10];

    u16* wsw      = (u16*)d_ws;
    float* biases = (float*)((char*)d_ws + 1638400);
    unsigned* bar = (unsigned*)((char*)d_ws + 1646592);

    prep_kernel<<<409, 256, 0, stream>>>(wih0, whh0, wih1, whh1,
                                         bih0, bhh0, bih1, bhh1, wsw, biases);
    lstm_fused<<<NBLK, 1024, 69632, stream>>>(x, wsw, biases, fcw, fcb,
                                              (float*)d_out, bar);
}